// Round 22
// baseline (770.772 us; speedup 1.0000x reference)
//
#include <hip/hip_runtime.h>
#include <hip/hip_bf16.h>

typedef __bf16 bf16;
typedef _Float16 fp16;
typedef __attribute__((ext_vector_type(8))) __bf16 bf16x8;
typedef __attribute__((ext_vector_type(4))) __bf16 bf16x4;
typedef __attribute__((ext_vector_type(4))) _Float16 fp16x4;
typedef __attribute__((ext_vector_type(4))) float f32x4;
typedef __attribute__((ext_vector_type(4))) unsigned int u32x4;
typedef long long i64;

#define H_IN 1342
#define TT   128
#define BB   128

static __device__ __forceinline__ f32x4 mfma16(bf16x8 a, bf16x8 b, f32x4 c) {
    return __builtin_amdgcn_mfma_f32_16x16x32_bf16(a, b, c, 0, 0, 0);
}
static __device__ __forceinline__ f32x4 mfma8(i64 a, i64 b, f32x4 c) {
    return __builtin_amdgcn_mfma_f32_16x16x32_fp8_fp8(a, b, c, 0, 0, 0);
}

// ---- native transcendentals (single HW instruction each) ----
static __device__ __forceinline__ float fexp2(float x) {
#if __has_builtin(__builtin_amdgcn_exp2f)
    return __builtin_amdgcn_exp2f(x);
#else
    float r; asm("v_exp_f32 %0, %1" : "=v"(r) : "v"(x)); return r;
#endif
}
static __device__ __forceinline__ float frcp(float x) {
#if __has_builtin(__builtin_amdgcn_rcpf)
    return __builtin_amdgcn_rcpf(x);
#else
    float r; asm("v_rcp_f32 %0, %1" : "=v"(r) : "v"(x)); return r;
#endif
}
static __device__ __forceinline__ float sigf(float x) {
    return frcp(1.f + fexp2(x * -1.44269504f));
}
static __device__ __forceinline__ float tanhfast(float x) {
    return __builtin_fmaf(2.f, frcp(1.f + fexp2(x * -2.88539008f)), -1.f);
}

// float -> OCP e4m3fn with RNE (software; one-time packing/prologue only).
static __device__ __forceinline__ unsigned char f2e4m3(float x) {
    unsigned char sgn = (unsigned char)((__builtin_bit_cast(unsigned int, x) >> 24) & 0x80);
    float ax = fabsf(x);
    if (ax < 0.015625f) {
        float q = nearbyintf(ax * 512.f);
        return sgn | (unsigned char)(int)q;
    }
    if (ax >= 448.f) return sgn | 0x7E;
    int e; float m = frexpf(ax, &e);
    float q = nearbyintf(m * 16.f);
    int E = e - 1;
    if (q == 16.f) { q = 8.f; E += 1; }
    if (E > 8) return sgn | 0x7E;
    return sgn | (unsigned char)((E + 7) << 3) | (unsigned char)((int)q & 7);
}

// Packed f32x2 -> 2 fp8 bytes — ALWAYS the hardware instruction.
static __device__ __forceinline__ unsigned int pk_fp8(float a, float b) {
#if __has_builtin(__builtin_amdgcn_cvt_pk_fp8_f32)
    return (unsigned int)__builtin_amdgcn_cvt_pk_fp8_f32(a, b, 0, false);
#else
    unsigned int r;
    asm("v_cvt_pk_fp8_f32 %0, %1, %2" : "=v"(r) : "v"(a), "v"(b));
    return r;
#endif
}

// ---------------------------------------------------------------------------
// Pack: (1) three w_hh matrices into fp8 MFMA B-fragment order;
//       (2) wih0 -> bf16 [768][1344] zero-padded; (3) wih1/2 -> bf16 [768][256].
// ---------------------------------------------------------------------------
__global__ void prep_pack3(const float* __restrict__ whh0,
                           const float* __restrict__ whh1,
                           const float* __restrict__ whh2,
                           const float* __restrict__ wih0,
                           const float* __restrict__ wih1,
                           const float* __restrict__ wih2,
                           unsigned char* __restrict__ Wh8,
                           bf16* __restrict__ Wb0,
                           bf16* __restrict__ Wb1,
                           bf16* __restrict__ Wb2)
{
    int idx = blockIdx.x * blockDim.x + threadIdx.x;
    if (idx < 589824) {
        int l = idx / 196608;
        int r = idx - l * 196608;
        const float* w = (l == 0) ? whh0 : (l == 1) ? whh1 : whh2;
        int f = r >> 9, q = r & 511;
        int lane = q >> 3, j = q & 7;
        int nt = f >> 3, kt = f & 7;
        int n = nt * 16 + (lane & 15);
        int k = kt * 32 + (lane >> 4) * 8 + j;
        Wh8[idx] = f2e4m3(w[n * 256 + k]);
    } else if (idx < 589824 + 1032192) {
        int i = idx - 589824;
        int n = i / 1344, k = i - n * 1344;
        Wb0[i] = (k < H_IN) ? (bf16)wih0[(size_t)n * H_IN + k] : (bf16)0.f;
    } else if (idx < 589824 + 1032192 + 196608) {
        int i = idx - (589824 + 1032192);
        Wb1[i] = (bf16)wih1[i];
    } else if (idx < 2015232) {
        int i = idx - (589824 + 1032192 + 196608);
        Wb2[i] = (bf16)wih2[i];
    }
}

// ---------------------------------------------------------------------------
// gx tile layout, per (t, g): 32 KB at gxt + ((t*8+g)<<15):
//   r-plane fp16 [col][row16] : off = col*32 + row*2
//   z-plane fp16 [col][row16] : off = 8192 + col*32 + row*2
//   n-plane fp32 [col][row16] : off = 16384 + col*64 + row*4
// ---------------------------------------------------------------------------
__global__ __launch_bounds__(512) void gemm_gx0(const float* __restrict__ X,
                                                const bf16* __restrict__ Wb,
                                                const float* __restrict__ bih,
                                                const float* __restrict__ bhh,
                                                char*  __restrict__ gxt)
{
    __shared__ bf16 As[128][40];
    __shared__ bf16 Bs[256][40];
    const int tid  = threadIdx.x;
    const int lane = tid & 63;
    const int w    = tid >> 6;
    const int cl   = lane & 15;
    const int lh   = lane >> 4;
    const int n0   = blockIdx.y * 256;

    f32x4 acc[16];
#pragma unroll
    for (int i = 0; i < 16; ++i) acc[i] = (f32x4){0.f, 0.f, 0.f, 0.f};

    for (int kt = 0; kt < 42; ++kt) {
        const int k0 = kt * 32;
        {   // A row rm = blockIdx.x*128 + row -> b=row, t=blockIdx.x
            int row = tid >> 2;
            int c   = (tid & 3) * 8;
            const float* src = X + ((size_t)row * 128 + blockIdx.x) * H_IN + (k0 + c);
            bf16x8 pk;
            if (k0 + c + 8 <= H_IN) {
                const float2* s2 = (const float2*)src;
                float2 v0 = s2[0], v1 = s2[1], v2 = s2[2], v3 = s2[3];
                pk[0] = (bf16)v0.x; pk[1] = (bf16)v0.y; pk[2] = (bf16)v1.x; pk[3] = (bf16)v1.y;
                pk[4] = (bf16)v2.x; pk[5] = (bf16)v2.y; pk[6] = (bf16)v3.x; pk[7] = (bf16)v3.y;
            } else {
#pragma unroll
                for (int i = 0; i < 8; ++i)
                    pk[i] = (bf16)((k0 + c + i < H_IN) ? src[i] : 0.f);
            }
            *(bf16x8*)&As[row][c] = pk;
        }
        {   // B: pure bf16 copy (Wb zero-padded to 1344)
            int row = tid >> 1;
            int c   = (tid & 1) * 16;
            const bf16* src = Wb + (size_t)(n0 + row) * 1344 + k0 + c;
            *(bf16x8*)&Bs[row][c]     = ((const bf16x8*)src)[0];
            *(bf16x8*)&Bs[row][c + 8] = ((const bf16x8*)src)[1];
        }
        __syncthreads();
        bf16x8 a = *(const bf16x8*)&As[w * 16 + cl][lh * 8];
#pragma unroll
        for (int nt = 0; nt < 16; ++nt) {
            bf16x8 b = *(const bf16x8*)&Bs[nt * 16 + cl][lh * 8];
            acc[nt] = mfma16(a, b, acc[nt]);
        }
        __syncthreads();
    }
    char* base = gxt + (((size_t)blockIdx.x * 8 + w) << 15);
#pragma unroll
    for (int nt = 0; nt < 16; ++nt) {
        const int col = n0 + nt * 16 + cl;
        if (col < 256) {
            fp16x4 pk;
#pragma unroll
            for (int r = 0; r < 4; ++r) pk[r] = (fp16)(acc[nt][r] + bih[col] + bhh[col]);
            *(fp16x4*)(base + col * 32 + 8 * lh) = pk;
        } else if (col < 512) {
            fp16x4 pk;
#pragma unroll
            for (int r = 0; r < 4; ++r) pk[r] = (fp16)(acc[nt][r] + bih[col] + bhh[col]);
            *(fp16x4*)(base + 8192 + (col - 256) * 32 + 8 * lh) = pk;
        } else {
            float4 pk = {acc[nt][0] + bih[col], acc[nt][1] + bih[col],
                         acc[nt][2] + bih[col], acc[nt][3] + bih[col]};
            *(float4*)(base + 16384 + (col - 512) * 64 + 16 * lh) = pk;
        }
    }
}

// Layers 1/2 input GEMM: A = Y bf16 [t*128+b][256], B = prepacked bf16.
__global__ __launch_bounds__(512) void gemm_gxy(const bf16* __restrict__ Y,
                                                const bf16* __restrict__ Wb,
                                                const float* __restrict__ bih,
                                                const float* __restrict__ bhh,
                                                char*  __restrict__ gxt)
{
    __shared__ bf16 As[128][40];
    __shared__ bf16 Bs[256][40];
    const int tid  = threadIdx.x;
    const int lane = tid & 63;
    const int w    = tid >> 6;
    const int cl   = lane & 15;
    const int lh   = lane >> 4;
    const int rm0  = blockIdx.x * 128;
    const int n0   = blockIdx.y * 256;

    f32x4 acc[16];
#pragma unroll
    for (int i = 0; i < 16; ++i) acc[i] = (f32x4){0.f, 0.f, 0.f, 0.f};

    for (int kt = 0; kt < 8; ++kt) {
        const int k0 = kt * 32;
        {
            int row = tid >> 2;
            int c   = (tid & 3) * 8;
            *(bf16x8*)&As[row][c] =
                *(const bf16x8*)(Y + (size_t)(rm0 + row) * 256 + k0 + c);
        }
        {
            int row = tid >> 1;
            int c   = (tid & 1) * 16;
            const bf16* src = Wb + (size_t)(n0 + row) * 256 + k0 + c;
            *(bf16x8*)&Bs[row][c]     = ((const bf16x8*)src)[0];
            *(bf16x8*)&Bs[row][c + 8] = ((const bf16x8*)src)[1];
        }
        __syncthreads();
        bf16x8 a = *(const bf16x8*)&As[w * 16 + cl][lh * 8];
#pragma unroll
        for (int nt = 0; nt < 16; ++nt) {
            bf16x8 b = *(const bf16x8*)&Bs[nt * 16 + cl][lh * 8];
            acc[nt] = mfma16(a, b, acc[nt]);
        }
        __syncthreads();
    }
    char* base = gxt + (((size_t)blockIdx.x * 8 + w) << 15);
#pragma unroll
    for (int nt = 0; nt < 16; ++nt) {
        const int col = n0 + nt * 16 + cl;
        if (col < 256) {
            fp16x4 pk;
#pragma unroll
            for (int r = 0; r < 4; ++r) pk[r] = (fp16)(acc[nt][r] + bih[col] + bhh[col]);
            *(fp16x4*)(base + col * 32 + 8 * lh) = pk;
        } else if (col < 512) {
            fp16x4 pk;
#pragma unroll
            for (int r = 0; r < 4; ++r) pk[r] = (fp16)(acc[nt][r] + bih[col] + bhh[col]);
            *(fp16x4*)(base + 8192 + (col - 256) * 32 + 8 * lh) = pk;
        } else {
            float4 pk = {acc[nt][0] + bih[col], acc[nt][1] + bih[col],
                         acc[nt][2] + bih[col], acc[nt][3] + bih[col]};
            *(float4*)(base + 16384 + (col - 512) * 64 + 16 * lh) = pk;
        }
    }
}

// ---------------------------------------------------------------------------
// Recurrent layer v15 (round-20 schedule, verified 191 us): r,z weights in
// LDS; n streamed; gx to regs; 16 waves; one barrier/step; Y epilogue at
// step head (overlaps gx-load latency). Y may be nullptr (layer 2).
// ---------------------------------------------------------------------------
__global__ __launch_bounds__(1024)
void gru_rec(
    const char* __restrict__ gxt,           // [T][8][32KB] transposed gx tiles
    const unsigned char* __restrict__ Wh8,  // this layer's fp8 hh pack
    const float* __restrict__ bhh,          // raw b_hh (768); only n-part used
    const float* __restrict__ h0,           // hidden + l*128*256
    bf16*  __restrict__ Y,                  // [T*B][256] bf16 out (or null)
    float* __restrict__ hnfL)               // hnf + l*256 (stride 768)
{
    __shared__ unsigned char WL[131072];               // r,z fp8 frags
    __shared__ unsigned char Ah8[2][16][264];          // fp8 h (MFMA A), db
    __shared__ bf16 Yst[2][16][264];                   // bf16 h (Y stage), db

    const int tid  = threadIdx.x;
    const int lane = tid & 63;
    const int w    = tid >> 6;              // 0..15 == col-tile
    const int cl   = lane & 15;
    const int lh   = lane >> 4;
    const int g    = blockIdx.x;
    const int col  = 16 * w + cl;

    // ---- one-time: r,z weight planes -> LDS ----
#pragma unroll
    for (int i = 0; i < 8; ++i) {
        const int off = (tid + i * 1024) * 16;
        *(u32x4*)&WL[off] = *(const u32x4*)(Wh8 + off);
    }
    const float bN = bhh[512 + col];

    // ---- prologue: h0 -> regs + Ah8[1] ----
    float hprev[4];
#pragma unroll
    for (int r = 0; r < 4; ++r) {
        const int m = 4 * lh + r;
        float v = h0[(size_t)(g * 16 + m) * 256 + col];
        hprev[r] = v;
        Ah8[1][m][col] = f2e4m3(v);
    }
    __syncthreads();   // WL + Ah8[1] staged

    for (int t = 0; t < TT; ++t) {
        const int slot = t & 1;
        const int rb   = (t + 1) & 1;

        // ---- Y epilogue for step t-1 (store stays in flight) ----
        if (Y && t > 0) {
            const int yrow = tid >> 6;          // 0..15
            const int yc   = (tid & 63) * 4;    // 0..252
            bf16x4 yv = *(const bf16x4*)&Yst[(t - 1) & 1][yrow][yc];
            *(bf16x4*)(Y + ((size_t)(t - 1) * BB + g * 16 + yrow) * 256 + yc) = yv;
        }

        // ---- issue gx(t) loads (regs) + n-weight loads (L2 stream) ----
        const char* gt = gxt + (((size_t)t * 8 + g) << 15);
        fp16x4 rv = *(const fp16x4*)(gt + col * 32 + 8 * lh);
        fp16x4 zv = *(const fp16x4*)(gt + 8192 + col * 32 + 8 * lh);
        f32x4  nv = *(const f32x4*) (gt + 16384 + col * 64 + 16 * lh);
        i64 Bn[8];
#pragma unroll
        for (int kk = 0; kk < 8; ++kk)
            Bn[kk] = *(const i64*)(Wh8 + (size_t)(((32 + w) * 8 + kk) * 512) + lane * 8);

        // ---- MFMA: r,z from LDS weights (a cached in regs), then n ----
        f32x4 cr = (f32x4){0.f,0.f,0.f,0.f};
        f32x4 cz = (f32x4){0.f,0.f,0.f,0.f};
        f32x4 cn = (f32x4){0.f,0.f,0.f,0.f};
        i64 areg[8];
        __builtin_amdgcn_s_setprio(1);
#pragma unroll
        for (int kk = 0; kk < 8; ++kk) {
            i64 a = *(const i64*)&Ah8[rb][cl][kk * 32 + lh * 8];
            areg[kk] = a;
            cr = mfma8(a, *(const i64*)&WL[(size_t)(( w       * 8 + kk) * 512) + lane * 8], cr);
            cz = mfma8(a, *(const i64*)&WL[(size_t)(((16 + w) * 8 + kk) * 512) + lane * 8], cz);
        }
#pragma unroll
        for (int kk = 0; kk < 8; ++kk)
            cn = mfma8(areg[kk], Bn[kk], cn);
        __builtin_amdgcn_s_setprio(0);

        // ---- gates: native exp2/rcp math, hardware fp8 pack ----
        float hn4[4];
#pragma unroll
        for (int r = 0; r < 4; ++r) {
            const int m = 4 * lh + r;
            float rr_ = sigf((float)rv[r] + cr[r]);
            float zz  = sigf((float)zv[r] + cz[r]);
            float nn  = tanhfast(__builtin_fmaf(rr_, cn[r] + bN, nv[r]));
            float hnew = __builtin_fmaf(zz, hprev[r] - nn, nn);
            hprev[r] = hnew;
            hn4[r] = hnew;
            Yst[slot][m][col] = (bf16)hnew;
        }
        {
            unsigned int p0 = pk_fp8(hn4[0], hn4[1]);
            unsigned int p1 = pk_fp8(hn4[2], hn4[3]);
            const int m0 = 4 * lh;
            Ah8[slot][m0 + 0][col] = (unsigned char)(p0 & 0xff);
            Ah8[slot][m0 + 1][col] = (unsigned char)((p0 >> 8) & 0xff);
            Ah8[slot][m0 + 2][col] = (unsigned char)(p1 & 0xff);
            Ah8[slot][m0 + 3][col] = (unsigned char)((p1 >> 8) & 0xff);
        }

        asm volatile("s_waitcnt lgkmcnt(0)" ::: "memory");
        __builtin_amdgcn_sched_barrier(0);
        __builtin_amdgcn_s_barrier();          // the ONLY barrier per step
        __builtin_amdgcn_sched_barrier(0);
    }

    // ---- final hnf + Y epilogue ----
#pragma unroll
    for (int r = 0; r < 4; ++r) {
        const int m = 4 * lh + r;
        hnfL[(size_t)(g * 16 + m) * 768 + col] = hprev[r];
    }
    if (Y) {
        const int yrow = tid >> 6;
        const int yc   = (tid & 63) * 4;
        bf16x4 yv = *(const bf16x4*)&Yst[(TT - 1) & 1][yrow][yc];
        *(bf16x4*)(Y + ((size_t)(TT - 1) * BB + g * 16 + yrow) * 256 + yc) = yv;
    }
}

// ---------------------------------------------------------------------------
// FC head as MFMA GEMM: out[b][n] = fc_b[n] + hn[b] . fc_w[n]
// ---------------------------------------------------------------------------
__global__ __launch_bounds__(512) void fc_gemm(const float* __restrict__ hn,
                                               const float* __restrict__ fcw,
                                               const float* __restrict__ fcb,
                                               float* __restrict__ out)
{
    __shared__ bf16 As[128][40];
    __shared__ bf16 Bs[256][40];
    const int tid  = threadIdx.x;
    const int lane = tid & 63;
    const int w    = tid >> 6;
    const int cl   = lane & 15;
    const int lh   = lane >> 4;
    const int n0   = blockIdx.x * 256;

    f32x4 acc[16];
#pragma unroll
    for (int i = 0; i < 16; ++i) acc[i] = (f32x4){0.f, 0.f, 0.f, 0.f};

    for (int kt = 0; kt < 24; ++kt) {
        const int k0 = kt * 32;
        {
            int row = tid >> 2;
            int c   = (tid & 3) * 8;
            const float2* s2 = (const float2*)(hn + (size_t)row * 768 + k0 + c);
            float2 v0 = s2[0], v1 = s2[1], v2 = s2[2], v3 = s2[3];
            bf16x8 pk;
            pk[0] = (bf16)v0.x; pk[1] = (bf16)v0.y; pk[2] = (bf16)v1.x; pk[3] = (bf16)v1.y;
            pk[4] = (bf16)v2.x; pk[5] = (bf16)v2.y; pk[6] = (bf16)v3.x; pk[7] = (bf16)v3.y;
            *(bf16x8*)&As[row][c] = pk;
        }
        {
            int row = tid >> 1;
            int c   = (tid & 1) * 16;
            const int n = n0 + row;
#pragma unroll
            for (int h = 0; h < 2; ++h) {
                bf16x8 pk;
                if (n < H_IN) {
                    const float2* s2 = (const float2*)(fcw + (size_t)n * 768 + k0 + c + h * 8);
                    float2 v0 = s2[0], v1 = s2[1], v2 = s2[2], v3 = s2[3];
                    pk[0] = (bf16)v0.x; pk[1] = (bf16)v0.y; pk[2] = (bf16)v1.x; pk[3] = (bf16)v1.y;
                    pk[4] = (bf16)v2.x; pk[5] = (bf16)v2.y; pk[6] = (bf16)v3.x; pk[7] = (bf16)v3.y;
                } else {
#pragma unroll
                    for (int i = 0; i < 8; ++i) pk[i] = (bf16)0.f;
                }
                *(bf16x8*)&Bs[row][c + h * 8] = pk;
            }
        }
        __syncthreads();
        bf16x8 a = *(const bf16x8*)&As[w * 16 + cl][lh * 8];
#pragma unroll
        for (int nt = 0; nt < 16; ++nt) {
            bf16x8 b = *(const bf16x8*)&Bs[nt * 16 + cl][lh * 8];
            acc[nt] = mfma16(a, b, acc[nt]);
        }
        __syncthreads();
    }
#pragma unroll
    for (int nt = 0; nt < 16; ++nt) {
#pragma unroll
        for (int r = 0; r < 4; ++r) {
            int b   = w * 16 + 4 * lh + r;
            int col = n0 + nt * 16 + cl;
            if (col < H_IN)
                out[(size_t)b * H_IN + col] = acc[nt][r] + fcb[col];
        }
    }
}

extern "C" void kernel_launch(void* const* d_in, const int* in_sizes, int n_in,
                              void* d_out, int out_size, void* d_ws, size_t ws_size,
                              hipStream_t stream) {
    const float* X    = (const float*)d_in[0];
    const float* hid  = (const float*)d_in[1];
    const float* wih0 = (const float*)d_in[2];
    const float* whh0 = (const float*)d_in[3];
    const float* bih0 = (const float*)d_in[4];
    const float* bhh0 = (const float*)d_in[5];
    const float* wih1 = (const float*)d_in[6];
    const float* whh1 = (const float*)d_in[7];
    const float* bih1 = (const float*)d_in[8];
    const float* bhh1 = (const float*)d_in[9];
    const float* wih2 = (const float*)d_in[10];
    const float* whh2 = (const float*)d_in[11];
    const float* bih2 = (const float*)d_in[12];
    const float* bhh2 = (const float*)d_in[13];
    const float* fcw  = (const float*)d_in[14];
    const float* fcb  = (const float*)d_in[15];
    float* out = (float*)d_out;

    // Layout (total 45,776,896 B — within the known-safe 52.7 MB):
    char* ws = (char*)d_ws;
    unsigned char* Wh8 = (unsigned char*)ws;       //          0 ..    589,824
    bf16*  Wb0  = (bf16*)(ws + 589824);            //    589,824 ..  2,654,208
    bf16*  Wb1  = (bf16*)(ws + 2654208);           //  2,654,208 ..  3,047,424
    bf16*  Wb2  = (bf16*)(ws + 3047424);           //  3,047,424 ..  3,440,640
    float* hnf  = (float*)(ws + 3440640);          //  3,440,640 ..  3,833,856
    bf16*  Y    = (bf16*)(ws + 3833856);           //  3,833,856 .. 12,222,464
    char*  gxt  = ws + 12222464;                   // 12,222,464 .. 45,776,896

    prep_pack3<<<dim3(3936), dim3(512), 0, stream>>>(whh0, whh1, whh2,
                                                     wih0, wih1, wih2,
                                                     Wh8, Wb0, Wb1, Wb2);
    // layer 0
    gemm_gx0<<<dim3(128, 3), dim3(512), 0, stream>>>(X, Wb0, bih0, bhh0, gxt);
    gru_rec<<<dim3(8), dim3(1024), 0, stream>>>(gxt, Wh8, bhh0, hid, Y, hnf);
    // layer 1
    gemm_gxy<<<dim3(128, 3), dim3(512), 0, stream>>>(Y, Wb1, bih1, bhh1, gxt);
    gru_rec<<<dim3(8), dim3(1024), 0, stream>>>(gxt, Wh8 + 196608, bhh1,
                                                hid + 32768, Y, hnf + 256);
    // layer 2
    gemm_gxy<<<dim3(128, 3), dim3(512), 0, stream>>>(Y, Wb2, bih2, bhh2, gxt);
    gru_rec<<<dim3(8), dim3(1024), 0, stream>>>(gxt, Wh8 + 393216, bhh2,
                                                hid + 65536, (bf16*)nullptr, hnf + 512);
    // head
    fc_gemm<<<dim3(6), dim3(512), 0, stream>>>(hnf, fcw, fcb, out);
    hipMemcpyAsync(out + 171776, hid, 98304 * sizeof(float),
                   hipMemcpyDeviceToDevice, stream);
}

// Round 23
// 734.421 us; speedup vs baseline: 1.0495x; 1.0495x over previous
//
#include <hip/hip_runtime.h>
#include <hip/hip_bf16.h>

typedef __bf16 bf16;
typedef _Float16 fp16;
typedef __attribute__((ext_vector_type(8))) __bf16 bf16x8;
typedef __attribute__((ext_vector_type(4))) __bf16 bf16x4;
typedef __attribute__((ext_vector_type(4))) _Float16 fp16x4;
typedef __attribute__((ext_vector_type(4))) float f32x4;
typedef __attribute__((ext_vector_type(4))) unsigned int u32x4;
typedef long long i64;

#define H_IN 1342
#define TT   128
#define BB   128

static __device__ __forceinline__ f32x4 mfma16(bf16x8 a, bf16x8 b, f32x4 c) {
    return __builtin_amdgcn_mfma_f32_16x16x32_bf16(a, b, c, 0, 0, 0);
}
static __device__ __forceinline__ f32x4 mfma8(i64 a, i64 b, f32x4 c) {
    return __builtin_amdgcn_mfma_f32_16x16x32_fp8_fp8(a, b, c, 0, 0, 0);
}

// ---- native transcendentals (single HW instruction each) ----
static __device__ __forceinline__ float fexp2(float x) {
#if __has_builtin(__builtin_amdgcn_exp2f)
    return __builtin_amdgcn_exp2f(x);
#else
    float r; asm("v_exp_f32 %0, %1" : "=v"(r) : "v"(x)); return r;
#endif
}
static __device__ __forceinline__ float frcp(float x) {
#if __has_builtin(__builtin_amdgcn_rcpf)
    return __builtin_amdgcn_rcpf(x);
#else
    float r; asm("v_rcp_f32 %0, %1" : "=v"(r) : "v"(x)); return r;
#endif
}
static __device__ __forceinline__ float sigf(float x) {
    return frcp(1.f + fexp2(x * -1.44269504f));
}
static __device__ __forceinline__ float tanhfast(float x) {
    return __builtin_fmaf(2.f, frcp(1.f + fexp2(x * -2.88539008f)), -1.f);
}

// float -> OCP e4m3fn with RNE (software; one-time packing/prologue only).
static __device__ __forceinline__ unsigned char f2e4m3(float x) {
    unsigned char sgn = (unsigned char)((__builtin_bit_cast(unsigned int, x) >> 24) & 0x80);
    float ax = fabsf(x);
    if (ax < 0.015625f) {
        float q = nearbyintf(ax * 512.f);
        return sgn | (unsigned char)(int)q;
    }
    if (ax >= 448.f) return sgn | 0x7E;
    int e; float m = frexpf(ax, &e);
    float q = nearbyintf(m * 16.f);
    int E = e - 1;
    if (q == 16.f) { q = 8.f; E += 1; }
    if (E > 8) return sgn | 0x7E;
    return sgn | (unsigned char)((E + 7) << 3) | (unsigned char)((int)q & 7);
}

// Packed f32x2 -> 2 fp8 bytes — ALWAYS the hardware instruction.
static __device__ __forceinline__ unsigned int pk_fp8(float a, float b) {
#if __has_builtin(__builtin_amdgcn_cvt_pk_fp8_f32)
    return (unsigned int)__builtin_amdgcn_cvt_pk_fp8_f32(a, b, 0, false);
#else
    unsigned int r;
    asm("v_cvt_pk_fp8_f32 %0, %1, %2" : "=v"(r) : "v"(a), "v"(b));
    return r;
#endif
}

// ---------------------------------------------------------------------------
// Pack: (1) three w_hh matrices into fp8 MFMA B-fragment order;
//       (2) wih0 -> bf16 [768][1344] zero-padded; (3) wih1/2 -> bf16 [768][256].
// ---------------------------------------------------------------------------
__global__ void prep_pack3(const float* __restrict__ whh0,
                           const float* __restrict__ whh1,
                           const float* __restrict__ whh2,
                           const float* __restrict__ wih0,
                           const float* __restrict__ wih1,
                           const float* __restrict__ wih2,
                           unsigned char* __restrict__ Wh8,
                           bf16* __restrict__ Wb0,
                           bf16* __restrict__ Wb1,
                           bf16* __restrict__ Wb2)
{
    int idx = blockIdx.x * blockDim.x + threadIdx.x;
    if (idx < 589824) {
        int l = idx / 196608;
        int r = idx - l * 196608;
        const float* w = (l == 0) ? whh0 : (l == 1) ? whh1 : whh2;
        int f = r >> 9, q = r & 511;
        int lane = q >> 3, j = q & 7;
        int nt = f >> 3, kt = f & 7;
        int n = nt * 16 + (lane & 15);
        int k = kt * 32 + (lane >> 4) * 8 + j;
        Wh8[idx] = f2e4m3(w[n * 256 + k]);
    } else if (idx < 589824 + 1032192) {
        int i = idx - 589824;
        int n = i / 1344, k = i - n * 1344;
        Wb0[i] = (k < H_IN) ? (bf16)wih0[(size_t)n * H_IN + k] : (bf16)0.f;
    } else if (idx < 589824 + 1032192 + 196608) {
        int i = idx - (589824 + 1032192);
        Wb1[i] = (bf16)wih1[i];
    } else if (idx < 2015232) {
        int i = idx - (589824 + 1032192 + 196608);
        Wb2[i] = (bf16)wih2[i];
    }
}

// ---------------------------------------------------------------------------
// gx tile layout, per (t, g): 32 KB at gxt + ((t*8+g)<<15):
//   r-plane fp16 [col][row16] : off = col*32 + row*2
//   z-plane fp16 [col][row16] : off = 8192 + col*32 + row*2
//   n-plane fp32 [col][row16] : off = 16384 + col*64 + row*4
// ---------------------------------------------------------------------------
__global__ __launch_bounds__(512) void gemm_gx0(const float* __restrict__ X,
                                                const bf16* __restrict__ Wb,
                                                const float* __restrict__ bih,
                                                const float* __restrict__ bhh,
                                                char*  __restrict__ gxt)
{
    __shared__ bf16 As[128][40];
    __shared__ bf16 Bs[256][40];
    const int tid  = threadIdx.x;
    const int lane = tid & 63;
    const int w    = tid >> 6;
    const int cl   = lane & 15;
    const int lh   = lane >> 4;
    const int n0   = blockIdx.y * 256;

    f32x4 acc[16];
#pragma unroll
    for (int i = 0; i < 16; ++i) acc[i] = (f32x4){0.f, 0.f, 0.f, 0.f};

    for (int kt = 0; kt < 42; ++kt) {
        const int k0 = kt * 32;
        {   // A row rm = blockIdx.x*128 + row -> b=row, t=blockIdx.x
            int row = tid >> 2;
            int c   = (tid & 3) * 8;
            const float* src = X + ((size_t)row * 128 + blockIdx.x) * H_IN + (k0 + c);
            bf16x8 pk;
            if (k0 + c + 8 <= H_IN) {
                const float2* s2 = (const float2*)src;
                float2 v0 = s2[0], v1 = s2[1], v2 = s2[2], v3 = s2[3];
                pk[0] = (bf16)v0.x; pk[1] = (bf16)v0.y; pk[2] = (bf16)v1.x; pk[3] = (bf16)v1.y;
                pk[4] = (bf16)v2.x; pk[5] = (bf16)v2.y; pk[6] = (bf16)v3.x; pk[7] = (bf16)v3.y;
            } else {
#pragma unroll
                for (int i = 0; i < 8; ++i)
                    pk[i] = (bf16)((k0 + c + i < H_IN) ? src[i] : 0.f);
            }
            *(bf16x8*)&As[row][c] = pk;
        }
        {   // B: pure bf16 copy (Wb zero-padded to 1344)
            int row = tid >> 1;
            int c   = (tid & 1) * 16;
            const bf16* src = Wb + (size_t)(n0 + row) * 1344 + k0 + c;
            *(bf16x8*)&Bs[row][c]     = ((const bf16x8*)src)[0];
            *(bf16x8*)&Bs[row][c + 8] = ((const bf16x8*)src)[1];
        }
        __syncthreads();
        bf16x8 a = *(const bf16x8*)&As[w * 16 + cl][lh * 8];
#pragma unroll
        for (int nt = 0; nt < 16; ++nt) {
            bf16x8 b = *(const bf16x8*)&Bs[nt * 16 + cl][lh * 8];
            acc[nt] = mfma16(a, b, acc[nt]);
        }
        __syncthreads();
    }
    char* base = gxt + (((size_t)blockIdx.x * 8 + w) << 15);
#pragma unroll
    for (int nt = 0; nt < 16; ++nt) {
        const int col = n0 + nt * 16 + cl;
        if (col < 256) {
            fp16x4 pk;
#pragma unroll
            for (int r = 0; r < 4; ++r) pk[r] = (fp16)(acc[nt][r] + bih[col] + bhh[col]);
            *(fp16x4*)(base + col * 32 + 8 * lh) = pk;
        } else if (col < 512) {
            fp16x4 pk;
#pragma unroll
            for (int r = 0; r < 4; ++r) pk[r] = (fp16)(acc[nt][r] + bih[col] + bhh[col]);
            *(fp16x4*)(base + 8192 + (col - 256) * 32 + 8 * lh) = pk;
        } else {
            float4 pk = {acc[nt][0] + bih[col], acc[nt][1] + bih[col],
                         acc[nt][2] + bih[col], acc[nt][3] + bih[col]};
            *(float4*)(base + 16384 + (col - 512) * 64 + 16 * lh) = pk;
        }
    }
}

// Layers 1/2 input GEMM: A = Y bf16 [t*128+b][256], B = prepacked bf16.
__global__ __launch_bounds__(512) void gemm_gxy(const bf16* __restrict__ Y,
                                                const bf16* __restrict__ Wb,
                                                const float* __restrict__ bih,
                                                const float* __restrict__ bhh,
                                                char*  __restrict__ gxt)
{
    __shared__ bf16 As[128][40];
    __shared__ bf16 Bs[256][40];
    const int tid  = threadIdx.x;
    const int lane = tid & 63;
    const int w    = tid >> 6;
    const int cl   = lane & 15;
    const int lh   = lane >> 4;
    const int rm0  = blockIdx.x * 128;
    const int n0   = blockIdx.y * 256;

    f32x4 acc[16];
#pragma unroll
    for (int i = 0; i < 16; ++i) acc[i] = (f32x4){0.f, 0.f, 0.f, 0.f};

    for (int kt = 0; kt < 8; ++kt) {
        const int k0 = kt * 32;
        {
            int row = tid >> 2;
            int c   = (tid & 3) * 8;
            *(bf16x8*)&As[row][c] =
                *(const bf16x8*)(Y + (size_t)(rm0 + row) * 256 + k0 + c);
        }
        {
            int row = tid >> 1;
            int c   = (tid & 1) * 16;
            const bf16* src = Wb + (size_t)(n0 + row) * 256 + k0 + c;
            *(bf16x8*)&Bs[row][c]     = ((const bf16x8*)src)[0];
            *(bf16x8*)&Bs[row][c + 8] = ((const bf16x8*)src)[1];
        }
        __syncthreads();
        bf16x8 a = *(const bf16x8*)&As[w * 16 + cl][lh * 8];
#pragma unroll
        for (int nt = 0; nt < 16; ++nt) {
            bf16x8 b = *(const bf16x8*)&Bs[nt * 16 + cl][lh * 8];
            acc[nt] = mfma16(a, b, acc[nt]);
        }
        __syncthreads();
    }
    char* base = gxt + (((size_t)blockIdx.x * 8 + w) << 15);
#pragma unroll
    for (int nt = 0; nt < 16; ++nt) {
        const int col = n0 + nt * 16 + cl;
        if (col < 256) {
            fp16x4 pk;
#pragma unroll
            for (int r = 0; r < 4; ++r) pk[r] = (fp16)(acc[nt][r] + bih[col] + bhh[col]);
            *(fp16x4*)(base + col * 32 + 8 * lh) = pk;
        } else if (col < 512) {
            fp16x4 pk;
#pragma unroll
            for (int r = 0; r < 4; ++r) pk[r] = (fp16)(acc[nt][r] + bih[col] + bhh[col]);
            *(fp16x4*)(base + 8192 + (col - 256) * 32 + 8 * lh) = pk;
        } else {
            float4 pk = {acc[nt][0] + bih[col], acc[nt][1] + bih[col],
                         acc[nt][2] + bih[col], acc[nt][3] + bih[col]};
            *(float4*)(base + 16384 + (col - 512) * 64 + 16 * lh) = pk;
        }
    }
}

// ---------------------------------------------------------------------------
// Recurrent layer v15 (round-20 schedule, best measured 191 us): r,z weights
// in LDS; n streamed; gx to regs; 16 waves; one barrier/step; Y epilogue at
// step head (overlaps gx-load latency), unconditional.
// ---------------------------------------------------------------------------
__global__ __launch_bounds__(1024)
void gru_rec(
    const char* __restrict__ gxt,           // [T][8][32KB] transposed gx tiles
    const unsigned char* __restrict__ Wh8,  // this layer's fp8 hh pack
    const float* __restrict__ bhh,          // raw b_hh (768); only n-part used
    const float* __restrict__ h0,           // hidden + l*128*256
    bf16*  __restrict__ Y,                  // [T*B][256] bf16 out
    float* __restrict__ hnfL)               // hnf + l*256 (stride 768)
{
    __shared__ unsigned char WL[131072];               // r,z fp8 frags
    __shared__ unsigned char Ah8[2][16][264];          // fp8 h (MFMA A), db
    __shared__ bf16 Yst[2][16][264];                   // bf16 h (Y stage), db

    const int tid  = threadIdx.x;
    const int lane = tid & 63;
    const int w    = tid >> 6;              // 0..15 == col-tile
    const int cl   = lane & 15;
    const int lh   = lane >> 4;
    const int g    = blockIdx.x;
    const int col  = 16 * w + cl;

    // ---- one-time: r,z weight planes -> LDS ----
#pragma unroll
    for (int i = 0; i < 8; ++i) {
        const int off = (tid + i * 1024) * 16;
        *(u32x4*)&WL[off] = *(const u32x4*)(Wh8 + off);
    }
    const float bN = bhh[512 + col];

    // ---- prologue: h0 -> regs + Ah8[1] ----
    float hprev[4];
#pragma unroll
    for (int r = 0; r < 4; ++r) {
        const int m = 4 * lh + r;
        float v = h0[(size_t)(g * 16 + m) * 256 + col];
        hprev[r] = v;
        Ah8[1][m][col] = f2e4m3(v);
    }
    __syncthreads();   // WL + Ah8[1] staged

    for (int t = 0; t < TT; ++t) {
        const int slot = t & 1;
        const int rb   = (t + 1) & 1;

        // ---- Y epilogue for step t-1 (store stays in flight) ----
        if (t > 0) {
            const int yrow = tid >> 6;          // 0..15
            const int yc   = (tid & 63) * 4;    // 0..252
            bf16x4 yv = *(const bf16x4*)&Yst[(t - 1) & 1][yrow][yc];
            *(bf16x4*)(Y + ((size_t)(t - 1) * BB + g * 16 + yrow) * 256 + yc) = yv;
        }

        // ---- issue gx(t) loads (regs) + n-weight loads (L2 stream) ----
        const char* gt = gxt + (((size_t)t * 8 + g) << 15);
        fp16x4 rv = *(const fp16x4*)(gt + col * 32 + 8 * lh);
        fp16x4 zv = *(const fp16x4*)(gt + 8192 + col * 32 + 8 * lh);
        f32x4  nv = *(const f32x4*) (gt + 16384 + col * 64 + 16 * lh);
        i64 Bn[8];
#pragma unroll
        for (int kk = 0; kk < 8; ++kk)
            Bn[kk] = *(const i64*)(Wh8 + (size_t)(((32 + w) * 8 + kk) * 512) + lane * 8);

        // ---- MFMA: r,z from LDS weights (a cached in regs), then n ----
        f32x4 cr = (f32x4){0.f,0.f,0.f,0.f};
        f32x4 cz = (f32x4){0.f,0.f,0.f,0.f};
        f32x4 cn = (f32x4){0.f,0.f,0.f,0.f};
        i64 areg[8];
        __builtin_amdgcn_s_setprio(1);
#pragma unroll
        for (int kk = 0; kk < 8; ++kk) {
            i64 a = *(const i64*)&Ah8[rb][cl][kk * 32 + lh * 8];
            areg[kk] = a;
            cr = mfma8(a, *(const i64*)&WL[(size_t)(( w       * 8 + kk) * 512) + lane * 8], cr);
            cz = mfma8(a, *(const i64*)&WL[(size_t)(((16 + w) * 8 + kk) * 512) + lane * 8], cz);
        }
#pragma unroll
        for (int kk = 0; kk < 8; ++kk)
            cn = mfma8(areg[kk], Bn[kk], cn);
        __builtin_amdgcn_s_setprio(0);

        // ---- gates: native exp2/rcp math, hardware fp8 pack ----
        float hn4[4];
#pragma unroll
        for (int r = 0; r < 4; ++r) {
            const int m = 4 * lh + r;
            float rr_ = sigf((float)rv[r] + cr[r]);
            float zz  = sigf((float)zv[r] + cz[r]);
            float nn  = tanhfast(__builtin_fmaf(rr_, cn[r] + bN, nv[r]));
            float hnew = __builtin_fmaf(zz, hprev[r] - nn, nn);
            hprev[r] = hnew;
            hn4[r] = hnew;
            Yst[slot][m][col] = (bf16)hnew;
        }
        {
            unsigned int p0 = pk_fp8(hn4[0], hn4[1]);
            unsigned int p1 = pk_fp8(hn4[2], hn4[3]);
            const int m0 = 4 * lh;
            Ah8[slot][m0 + 0][col] = (unsigned char)(p0 & 0xff);
            Ah8[slot][m0 + 1][col] = (unsigned char)((p0 >> 8) & 0xff);
            Ah8[slot][m0 + 2][col] = (unsigned char)(p1 & 0xff);
            Ah8[slot][m0 + 3][col] = (unsigned char)((p1 >> 8) & 0xff);
        }

        asm volatile("s_waitcnt lgkmcnt(0)" ::: "memory");
        __builtin_amdgcn_sched_barrier(0);
        __builtin_amdgcn_s_barrier();          // the ONLY barrier per step
        __builtin_amdgcn_sched_barrier(0);
    }

    // ---- final hnf + Y epilogue ----
#pragma unroll
    for (int r = 0; r < 4; ++r) {
        const int m = 4 * lh + r;
        hnfL[(size_t)(g * 16 + m) * 768 + col] = hprev[r];
    }
    {
        const int yrow = tid >> 6;
        const int yc   = (tid & 63) * 4;
        bf16x4 yv = *(const bf16x4*)&Yst[(TT - 1) & 1][yrow][yc];
        *(bf16x4*)(Y + ((size_t)(TT - 1) * BB + g * 16 + yrow) * 256 + yc) = yv;
    }
}

// ---------------------------------------------------------------------------
// FC head as MFMA GEMM: out[b][n] = fc_b[n] + hn[b] . fc_w[n]
// ---------------------------------------------------------------------------
__global__ __launch_bounds__(512) void fc_gemm(const float* __restrict__ hn,
                                               const float* __restrict__ fcw,
                                               const float* __restrict__ fcb,
                                               float* __restrict__ out)
{
    __shared__ bf16 As[128][40];
    __shared__ bf16 Bs[256][40];
    const int tid  = threadIdx.x;
    const int lane = tid & 63;
    const int w    = tid >> 6;
    const int cl   = lane & 15;
    const int lh   = lane >> 4;
    const int n0   = blockIdx.x * 256;

    f32x4 acc[16];
#pragma unroll
    for (int i = 0; i < 16; ++i) acc[i] = (f32x4){0.f, 0.f, 0.f, 0.f};

    for (int kt = 0; kt < 24; ++kt) {
        const int k0 = kt * 32;
        {
            int row = tid >> 2;
            int c   = (tid & 3) * 8;
            const float2* s2 = (const float2*)(hn + (size_t)row * 768 + k0 + c);
            float2 v0 = s2[0], v1 = s2[1], v2 = s2[2], v3 = s2[3];
            bf16x8 pk;
            pk[0] = (bf16)v0.x; pk[1] = (bf16)v0.y; pk[2] = (bf16)v1.x; pk[3] = (bf16)v1.y;
            pk[4] = (bf16)v2.x; pk[5] = (bf16)v2.y; pk[6] = (bf16)v3.x; pk[7] = (bf16)v3.y;
            *(bf16x8*)&As[row][c] = pk;
        }
        {
            int row = tid >> 1;
            int c   = (tid & 1) * 16;
            const int n = n0 + row;
#pragma unroll
            for (int h = 0; h < 2; ++h) {
                bf16x8 pk;
                if (n < H_IN) {
                    const float2* s2 = (const float2*)(fcw + (size_t)n * 768 + k0 + c + h * 8);
                    float2 v0 = s2[0], v1 = s2[1], v2 = s2[2], v3 = s2[3];
                    pk[0] = (bf16)v0.x; pk[1] = (bf16)v0.y; pk[2] = (bf16)v1.x; pk[3] = (bf16)v1.y;
                    pk[4] = (bf16)v2.x; pk[5] = (bf16)v2.y; pk[6] = (bf16)v3.x; pk[7] = (bf16)v3.y;
                } else {
#pragma unroll
                    for (int i = 0; i < 8; ++i) pk[i] = (bf16)0.f;
                }
                *(bf16x8*)&Bs[row][c + h * 8] = pk;
            }
        }
        __syncthreads();
        bf16x8 a = *(const bf16x8*)&As[w * 16 + cl][lh * 8];
#pragma unroll
        for (int nt = 0; nt < 16; ++nt) {
            bf16x8 b = *(const bf16x8*)&Bs[nt * 16 + cl][lh * 8];
            acc[nt] = mfma16(a, b, acc[nt]);
        }
        __syncthreads();
    }
#pragma unroll
    for (int nt = 0; nt < 16; ++nt) {
#pragma unroll
        for (int r = 0; r < 4; ++r) {
            int b   = w * 16 + 4 * lh + r;
            int col = n0 + nt * 16 + cl;
            if (col < H_IN)
                out[(size_t)b * H_IN + col] = acc[nt][r] + fcb[col];
        }
    }
}

extern "C" void kernel_launch(void* const* d_in, const int* in_sizes, int n_in,
                              void* d_out, int out_size, void* d_ws, size_t ws_size,
                              hipStream_t stream) {
    const float* X    = (const float*)d_in[0];
    const float* hid  = (const float*)d_in[1];
    const float* wih0 = (const float*)d_in[2];
    const float* whh0 = (const float*)d_in[3];
    const float* bih0 = (const float*)d_in[4];
    const float* bhh0 = (const float*)d_in[5];
    const float* wih1 = (const float*)d_in[6];
    const float* whh1 = (const float*)d_in[7];
    const float* bih1 = (const float*)d_in[8];
    const float* bhh1 = (const float*)d_in[9];
    const float* wih2 = (const float*)d_in[10];
    const float* whh2 = (const float*)d_in[11];
    const float* bih2 = (const float*)d_in[12];
    const float* bhh2 = (const float*)d_in[13];
    const float* fcw  = (const float*)d_in[14];
    const float* fcb  = (const float*)d_in[15];
    float* out = (float*)d_out;

    // Layout (total 45,776,896 B — within the known-safe 52.7 MB):
    char* ws = (char*)d_ws;
    unsigned char* Wh8 = (unsigned char*)ws;       //          0 ..    589,824
    bf16*  Wb0  = (bf16*)(ws + 589824);            //    589,824 ..  2,654,208
    bf16*  Wb1  = (bf16*)(ws + 2654208);           //  2,654,208 ..  3,047,424
    bf16*  Wb2  = (bf16*)(ws + 3047424);           //  3,047,424 ..  3,440,640
    float* hnf  = (float*)(ws + 3440640);          //  3,440,640 ..  3,833,856
    bf16*  Y    = (bf16*)(ws + 3833856);           //  3,833,856 .. 12,222,464
    char*  gxt  = ws + 12222464;                   // 12,222,464 .. 45,776,896

    prep_pack3<<<dim3(3936), dim3(512), 0, stream>>>(whh0, whh1, whh2,
                                                     wih0, wih1, wih2,
                                                     Wh8, Wb0, Wb1, Wb2);
    // layer 0
    gemm_gx0<<<dim3(128, 3), dim3(512), 0, stream>>>(X, Wb0, bih0, bhh0, gxt);
    gru_rec<<<dim3(8), dim3(1024), 0, stream>>>(gxt, Wh8, bhh0, hid, Y, hnf);
    // layer 1
    gemm_gxy<<<dim3(128, 3), dim3(512), 0, stream>>>(Y, Wb1, bih1, bhh1, gxt);
    gru_rec<<<dim3(8), dim3(1024), 0, stream>>>(gxt, Wh8 + 196608, bhh1,
                                                hid + 32768, Y, hnf + 256);
    // layer 2
    gemm_gxy<<<dim3(128, 3), dim3(512), 0, stream>>>(Y, Wb2, bih2, bhh2, gxt);
    gru_rec<<<dim3(8), dim3(1024), 0, stream>>>(gxt, Wh8 + 393216, bhh2,
                                                hid + 65536, Y, hnf + 512);
    // head
    fc_gemm<<<dim3(6), dim3(512), 0, stream>>>(hnf, fcw, fcb, out);
    hipMemcpyAsync(out + 171776, hid, 98304 * sizeof(float),
                   hipMemcpyDeviceToDevice, stream);
}